// Round 1
// 581.629 us; speedup vs baseline: 1.0149x; 1.0149x over previous
//
#include <hip/hip_runtime.h>
#include <hip/hip_bf16.h>

// MultiheadAttention (heads=1 due to reference bug): B=4, N=4096, D=512, PROJ=512.
// scale = 1/sqrt(64) = 0.125. Inputs fp32, output fp32, internal bf16 MFMA.
//
// Pipeline (6 launches on stream):
//  1. transpose_w           Wt[n][k] (bf16) = W[k][n] (fp32) for w_q,w_k,w_v,w_mha
//  2. gemm_bt_bias<1,0,0>   qp = q @ Wq + b    (M=16384, K=512, N=512, A fp32, C bf16)
//  3. gemm_bt_bias<1,0,0>   kp = k @ Wk + b
//  4. gemm_bt_bias<1,1,0>   vpT[b][e][j] = (v @ Wv + b)[b][j][e]   (transposed epilogue)
//  5. flash_attn            dpa = softmax(qp kp^T * 0.125) @ vp  (online softmax, Tk=64)
//  6. gemm_bt_bias<0,0,1>   out = dpa @ w_mha + b_mha -> d_out (FP32)
//
// R3 flash_attn rewrite (counters: MfmaUtil 16%, 3.9e7 bank-conflicts, 10 barriers/iter):
//  - full-chunk K (64x512) and V (512x64) staged via global_load_lds w=16,
//    XOR-swizzled via pre-swizzled global source (LDS dest stays linear).
//  - XOR-swizzled b128 reads (K: slot^row&15, V/P: slot^row&7) -> uniform banks.
//  - in-register online softmax (shfl_xor 16-lane reduce + one cross-wc LDS merge);
//    Sld buffer eliminated; m/l/alpha in registers aligned with O-acc rows.
//  - 3 barriers/iter; K(t+1) prefetched during PV, V(t+1) during next QK^T.
//
// ws layout (shorts): qp, kp, vpT, dpa (8388608 each), Wt (4*262144) = 69 MB.

typedef __attribute__((ext_vector_type(8))) short bf16x8;
typedef __attribute__((ext_vector_type(4))) float f32x4;

#define NB 4
#define NN 4096
#define ND 512

__device__ __forceinline__ f32x4 mfma16(bf16x8 a, bf16x8 b, f32x4 c) {
    return __builtin_amdgcn_mfma_f32_16x16x32_bf16(a, b, c, 0, 0, 0);
}
__device__ __forceinline__ short f2bf(float f) {
    __hip_bfloat16 h = __float2bfloat16(f);
    return *reinterpret_cast<short*>(&h);
}

typedef __attribute__((address_space(1))) const unsigned int gls_gt;
typedef __attribute__((address_space(3))) unsigned int gls_lt;
__device__ __forceinline__ void gll16(const void* g, void* l) {
    __builtin_amdgcn_global_load_lds((gls_gt*)g, (gls_lt*)l, 16, 0, 0);
}

// ---------------- weight transpose: Wt[c][r] (bf16) = W[r][c] (fp32), 512x512 ----
struct Ptrs4 {
    const float* in[4];
    short* out[4];
};

__global__ void transpose_w(Ptrs4 p) {
    __shared__ short tile[32][33];
    const float* in = p.in[blockIdx.z];
    short* out = p.out[blockIdx.z];
    int r0 = blockIdx.y * 32, c0 = blockIdx.x * 32;
    int tx = threadIdx.x, ty = threadIdx.y;  // 32 x 8
    for (int i = 0; i < 32; i += 8)
        tile[ty + i][tx] = f2bf(in[(r0 + ty + i) * 512 + c0 + tx]);
    __syncthreads();
    for (int i = 0; i < 32; i += 8)
        out[(c0 + ty + i) * 512 + r0 + tx] = tile[tx][ty + i];
}

// ---------------- bt-form GEMM + bias: C[m][n] = sum_k A[m][k]*Bt[n][k] + bias[n] ----
template <int AF32, int VT, int OF32>
__global__ __launch_bounds__(256, 4) void gemm_bt_bias(
    const void* __restrict__ Av, const short* __restrict__ Bt,
    const float* __restrict__ bias, void* __restrict__ C) {
    __shared__ short As[64][72];
    __shared__ short Bs[64][72];
    int tid = threadIdx.x;
    int lane = tid & 63, w = tid >> 6;
    int l15 = lane & 15, l4 = lane >> 4;
    int wr = (w & 1) * 32, wcn = (w >> 1) * 32;
    int m0 = blockIdx.y * 64, n0 = blockIdx.x * 64;
    f32x4 acc[4] = {};  // [mi*2+ni]
    int srow = tid >> 3, scol8 = (tid & 7) * 8;
    for (int kt = 0; kt < 512; kt += 64) {
        __syncthreads();
        for (int i = 0; i < 64; i += 32) {
            int r = srow + i;
            if (AF32) {
                const float* A = (const float*)Av;
                const float* src = &A[(size_t)(m0 + r) * 512 + kt + scol8];
                float4 f0 = *(const float4*)src;
                float4 f1 = *(const float4*)(src + 4);
                short tmp[8];
                tmp[0] = f2bf(f0.x); tmp[1] = f2bf(f0.y);
                tmp[2] = f2bf(f0.z); tmp[3] = f2bf(f0.w);
                tmp[4] = f2bf(f1.x); tmp[5] = f2bf(f1.y);
                tmp[6] = f2bf(f1.z); tmp[7] = f2bf(f1.w);
                *(bf16x8*)&As[r][scol8] = *(bf16x8*)tmp;
            } else {
                const short* A = (const short*)Av;
                *(bf16x8*)&As[r][scol8] = *(const bf16x8*)&A[(size_t)(m0 + r) * 512 + kt + scol8];
            }
            *(bf16x8*)&Bs[r][scol8] = *(const bf16x8*)&Bt[(n0 + r) * 512 + kt + scol8];
        }
        __syncthreads();
        for (int kb = 0; kb < 2; kb++) {
            int ko = kb * 32 + l4 * 8;
            bf16x8 a0 = *(const bf16x8*)&As[wr + l15][ko];
            bf16x8 a1 = *(const bf16x8*)&As[wr + 16 + l15][ko];
            bf16x8 b0 = *(const bf16x8*)&Bs[wcn + l15][ko];
            bf16x8 b1 = *(const bf16x8*)&Bs[wcn + 16 + l15][ko];
            acc[0] = mfma16(a0, b0, acc[0]);
            acc[1] = mfma16(a0, b1, acc[1]);
            acc[2] = mfma16(a1, b0, acc[2]);
            acc[3] = mfma16(a1, b1, acc[3]);
        }
    }
    for (int mi = 0; mi < 2; mi++)
        for (int ni = 0; ni < 2; ni++) {
            f32x4 vv = acc[mi * 2 + ni];
            int col = n0 + wcn + ni * 16 + l15;
            float bv = bias[col];
            for (int r = 0; r < 4; r++) {
                int row = m0 + wr + mi * 16 + l4 * 4 + r;
                float val = vv[r] + bv;
                if (VT) {
                    int b = row >> 12, j = row & 4095;
                    ((short*)C)[(size_t)b * (ND * NN) + (size_t)col * NN + j] = f2bf(val);
                } else if (OF32) {
                    ((float*)C)[(size_t)row * 512 + col] = val;
                } else {
                    ((short*)C)[(size_t)row * 512 + col] = f2bf(val);
                }
            }
        }
}

// ---------------- flash attention ----------------
// Block: 64 Q-rows of one batch, 512 threads (8 waves: wr 0..3 q-16-blocks x wc 0..1
// key/e-halves). Q persistent in regs. Full 64-key chunk staged per iteration.
// LDS 140 KB (1 block/CU): Ks 64x512 bf16 (slot^row&15), Vs 512x64 bf16 (slot^row&7),
// Pld 64x64 bf16 (slot^row&7), Sex stats. 3 barriers/iter, both stages prefetched.
__global__ __launch_bounds__(512, 2) void flash_attn(
    const short* __restrict__ qp, const short* __restrict__ kp,
    const short* __restrict__ vpT, short* __restrict__ dpa) {
    __shared__ __align__(1024) char KsB[65536];
    __shared__ __align__(1024) char VsB[65536];
    __shared__ __align__(16)   char PldB[8192];
    __shared__ float SexM[128];   // [wc][row] half-max
    __shared__ float SexS[128];   // [wc][row] half-sum

    int tid = threadIdx.x;
    int lane = tid & 63, w = tid >> 6;
    int l15 = lane & 15, l4 = lane >> 4;
    int wr = w & 3;    // q 16-row block
    int wc = w >> 2;   // key/e half
    int b = blockIdx.y;
    int q0 = blockIdx.x * 64;

    const short* qpb = qp + b * (NN * ND);
    const short* kpb = kp + b * (NN * ND);
    const short* vtb = vpT + b * (ND * NN);

    // persistent Q fragments: A-row = l15 (q-row q0+wr*16+l15), k = kb*32 + l4*8
    bf16x8 qf[16];
    {
        const short* qrow = qpb + (q0 + wr * 16 + l15) * ND + l4 * 8;
#pragma unroll
        for (int kb = 0; kb < 16; kb++) qf[kb] = *(const bf16x8*)(qrow + kb * 32);
    }
    f32x4 oacc[16] = {};
    float m_run[4], l_run[4];
#pragma unroll
    for (int r = 0; r < 4; r++) { m_run[r] = -1e30f; l_run[r] = 0.f; }

    // swizzled 16B-slot byte offsets for V/P reads (row&7 == l15&7 on all read rows)
    const int vsl0 = ((l4 ^ (l15 & 7)) << 4);
    const int vsl1 = vsl0 ^ 64;

    // K row r (1024B): physical slot p holds logical 16B chunk d = p ^ (r&15).
    // gll writes lane l at slot l -> lane loads global chunk l ^ (r&15).
#define STAGE_K(J0)                                                         \
    {                                                                       \
        _Pragma("unroll")                                                   \
        for (int c = 0; c < 8; c++) {                                       \
            int key = w * 8 + c;                                            \
            const short* src = kpb + (size_t)((J0) + key) * ND +            \
                               ((lane ^ (key & 15)) << 3);                  \
            gll16(src, KsB + key * 1024);                                   \
        }                                                                   \
    }
    // V e-row (128B, 8 slots): slot p holds chunk p ^ (e&7). One gll = 8 e-rows.
#define STAGE_V(J0)                                                         \
    {                                                                       \
        _Pragma("unroll")                                                   \
        for (int c = 0; c < 8; c++) {                                       \
            int g = w * 8 + c;                                              \
            int e = g * 8 + (lane >> 3);                                    \
            const short* src = vtb + (size_t)e * NN + (J0) +                \
                               (((lane & 7) ^ (e & 7)) << 3);               \
            gll16(src, VsB + g * 1024);                                     \
        }                                                                   \
    }

    STAGE_K(0);
    STAGE_V(0);
    __syncthreads();

    for (int j0 = 0; j0 < NN; j0 += 64) {
        // ---- S = Q K^T : C[m=q (l4*4+r)][n=key (l15)], keys wc*32 + t*16 + l15 ----
        f32x4 s0 = {}, s1 = {};
        {
            const char* kb0 = KsB + (32 * wc + l15) * 1024;
            const char* kb1 = kb0 + 16 * 1024;
#pragma unroll
            for (int kb = 0; kb < 16; kb++) {
                int sl = ((((kb << 2) | l4) ^ l15) << 4);   // (key&15)==l15 for both tiles
                s0 = mfma16(qf[kb], *(const bf16x8*)(kb0 + sl), s0);
                s1 = mfma16(qf[kb], *(const bf16x8*)(kb1 + sl), s1);
            }
        }
        // ---- in-register half softmax stats (over this wc's 32 keys) ----
        float vv0[4], vv1[4], mx[4], ss[4], p0[4], p1[4];
#pragma unroll
        for (int r = 0; r < 4; r++) {
            vv0[r] = s0[r] * 0.125f;
            vv1[r] = s1[r] * 0.125f;
            mx[r] = fmaxf(vv0[r], vv1[r]);
        }
#pragma unroll
        for (int off = 1; off <= 8; off <<= 1) {
#pragma unroll
            for (int r = 0; r < 4; r++) mx[r] = fmaxf(mx[r], __shfl_xor(mx[r], off));
        }
#pragma unroll
        for (int r = 0; r < 4; r++) {
            p0[r] = __expf(vv0[r] - mx[r]);
            p1[r] = __expf(vv1[r] - mx[r]);
            ss[r] = p0[r] + p1[r];
        }
#pragma unroll
        for (int off = 1; off <= 8; off <<= 1) {
#pragma unroll
            for (int r = 0; r < 4; r++) ss[r] += __shfl_xor(ss[r], off);
        }
        int row4 = wr * 16 + l4 * 4;
        if (l15 == 0) {
#pragma unroll
            for (int r = 0; r < 4; r++) {
                SexM[wc * 64 + row4 + r] = mx[r];
                SexS[wc * 64 + row4 + r] = ss[r];
            }
        }
        __syncthreads();   // A: Sex visible; V(t) stage drained
        // ---- merge halves, running (m,l) update, write P bf16, rescale O ----
#pragma unroll
        for (int r = 0; r < 4; r++) {
            int row = row4 + r;
            float mo = SexM[(wc ^ 1) * 64 + row];
            float so = SexS[(wc ^ 1) * 64 + row];
            float mt = fmaxf(mx[r], mo);
            float st = ss[r] * __expf(mx[r] - mt) + so * __expf(mo - mt);
            float mn = fmaxf(m_run[r], mt);
            float al = __expf(m_run[r] - mn);
            l_run[r] = l_run[r] * al + st * __expf(mt - mn);
            m_run[r] = mn;
            float fs = __expf(mx[r] - mn);
            int rw7 = row & 7;
            char* prow = PldB + row * 128;
            int col0 = wc * 32 + l15;
            *(short*)(prow + (((col0 >> 3) ^ rw7) << 4) + ((col0 & 7) << 1)) = f2bf(p0[r] * fs);
            int col1 = col0 + 16;
            *(short*)(prow + (((col1 >> 3) ^ rw7) << 4) + ((col1 & 7) << 1)) = f2bf(p1[r] * fs);
#pragma unroll
            for (int t = 0; t < 16; t++) oacc[t][r] *= al;
        }
        __syncthreads();   // B: Pld visible
        if (j0 + 64 < NN) STAGE_K(j0 + 64);   // lands during PV, drains at barrier C
        // ---- O += P V ----
        bf16x8 pa0, pa1;
        {
            const char* prow = PldB + (wr * 16 + l15) * 128;
            pa0 = *(const bf16x8*)(prow + vsl0);   // keys 0..31  (chunk l4)
            pa1 = *(const bf16x8*)(prow + vsl1);   // keys 32..63 (chunk 4+l4)
        }
#pragma unroll
        for (int eh = 0; eh < 2; eh++) {
#pragma unroll
            for (int i = 0; i < 8; i++) {
                const char* vb = VsB + (eh * 256 + 32 * i + 16 * wc + l15) * 128;
                int oi = eh * 8 + i;
                oacc[oi] = mfma16(pa0, *(const bf16x8*)(vb + vsl0), oacc[oi]);
                oacc[oi] = mfma16(pa1, *(const bf16x8*)(vb + vsl1), oacc[oi]);
            }
        }
        __syncthreads();   // C: PV done; K(t+1) drained
        if (j0 + 64 < NN) STAGE_V(j0 + 64);   // lands during next QK^T, drains at A
    }
    // ---- finalize: O /= l, store dpa ----
    float li[4];
#pragma unroll
    for (int r = 0; r < 4; r++) li[r] = 1.f / l_run[r];
    short* dpb = dpa + b * (NN * ND);
#pragma unroll
    for (int eh = 0; eh < 2; eh++)
#pragma unroll
        for (int i = 0; i < 8; i++) {
            int col = (16 * eh + 2 * i + wc) * 16 + l15;
#pragma unroll
            for (int r = 0; r < 4; r++) {
                int row = q0 + wr * 16 + l4 * 4 + r;
                dpb[row * ND + col] = f2bf(oacc[eh * 8 + i][r] * li[r]);
            }
        }
}

extern "C" void kernel_launch(void* const* d_in, const int* in_sizes, int n_in,
                              void* d_out, int out_size, void* d_ws, size_t ws_size,
                              hipStream_t stream) {
    const float* q     = (const float*)d_in[0];
    const float* k     = (const float*)d_in[1];
    const float* v     = (const float*)d_in[2];
    const float* w_q   = (const float*)d_in[3];
    const float* w_k   = (const float*)d_in[4];
    const float* w_v   = (const float*)d_in[5];
    const float* w_mha = (const float*)d_in[6];
    const float* b_q   = (const float*)d_in[7];
    const float* b_k   = (const float*)d_in[8];
    const float* b_v   = (const float*)d_in[9];
    const float* b_mha = (const float*)d_in[10];

    const size_t T = (size_t)NB * NN * ND;  // 8388608
    short* ws  = (short*)d_ws;
    short* qp  = ws;
    short* kp  = qp + T;
    short* vpT = kp + T;
    short* dpa = vpT + T;
    short* Wt  = dpa + T;  // 4 * 262144 shorts

    Ptrs4 p;
    p.in[0] = w_q;   p.out[0] = Wt;
    p.in[1] = w_k;   p.out[1] = Wt + 262144;
    p.in[2] = w_v;   p.out[2] = Wt + 524288;
    p.in[3] = w_mha; p.out[3] = Wt + 786432;
    transpose_w<<<dim3(16, 16, 4), dim3(32, 8), 0, stream>>>(p);

    gemm_bt_bias<1, 0, 0><<<dim3(8, 256), 256, 0, stream>>>(q, Wt,          b_q, qp);
    gemm_bt_bias<1, 0, 0><<<dim3(8, 256), 256, 0, stream>>>(k, Wt + 262144, b_k, kp);
    gemm_bt_bias<1, 1, 0><<<dim3(8, 256), 256, 0, stream>>>(v, Wt + 524288, b_v, vpT);

    flash_attn<<<dim3(64, 4), 512, 0, stream>>>(qp, kp, vpT, dpa);

    gemm_bt_bias<0, 0, 1><<<dim3(8, 256), 256, 0, stream>>>(dpa, Wt + 786432, b_mha, d_out);
}